// Round 3
// baseline (378.569 us; speedup 1.0000x reference)
//
#include <hip/hip_runtime.h>
#include <hip/hip_bf16.h>

// Problem constants
constexpr int   DIMC  = 512;
constexpr int   PARTC = 6;
constexpr int   NTOK  = 162;
constexpr float SCALING = 22.62741699796952f; // sqrt(512)
constexpr float LNEPS   = 1e-5f;
constexpr int   CHUNK = 16;   // tokens per online-softmax chunk (32KB of x = L1-resident)

typedef __attribute__((ext_vector_type(8))) short bf16x8;
typedef __attribute__((ext_vector_type(4))) float f32x4;

// ---------------------------------------------------------------------------
// K0: transpose f32 [R][C] -> bf16 [C][R]
// ---------------------------------------------------------------------------
__global__ __launch_bounds__(256) void transpose_f32_bf16(
    const float* __restrict__ in, __hip_bfloat16* __restrict__ outp, int R, int C)
{
  __shared__ float tile[32][33];
  const int tx = threadIdx.x, ty = threadIdx.y;
  const int bx = blockIdx.x, by = blockIdx.y;
  const int c = bx * 32 + tx;
#pragma unroll
  for (int i = 0; i < 32; i += 8) {
    int r = by * 32 + ty + i;
    tile[ty + i][tx] = in[(size_t)r * C + c];
  }
  __syncthreads();
#pragma unroll
  for (int i = 0; i < 32; i += 8) {
    outp[(size_t)(bx * 32 + ty + i) * R + by * 32 + tx] =
        __float2bfloat16(tile[tx][ty + i]);
  }
}

// ---------------------------------------------------------------------------
// K1: per-batch fused attention (online softmax) + /sqrt(512) + LayerNorm
//     out: bf16 [1024*6][512]
// One block per b; thread t owns dims d=t and d=t+256 of all 6 part rows.
// ---------------------------------------------------------------------------
__global__ __launch_bounds__(256) void attn_ln_k(
    const float* __restrict__ x,     // [1024][162][512]
    const float* __restrict__ pt,    // [6][512]
    const float* __restrict__ g,     // [512]
    const float* __restrict__ bta,   // [512]
    __hip_bfloat16* __restrict__ outp)
{
  const int b = blockIdx.x;
  const int tid = threadIdx.x;
  const int w = tid >> 6;
  const int lane = tid & 63;
  const float* __restrict__ xb = x + (size_t)b * (NTOK * DIMC);

  // part_tokens fragments for the logit pass: lane covers d in [4l,4l+4) and [256+4l, ...)
  float4 pA[PARTC], pB[PARTC];
#pragma unroll
  for (int p = 0; p < PARTC; ++p) {
    pA[p] = *(const float4*)(pt + p * DIMC + 4 * lane);
    pB[p] = *(const float4*)(pt + p * DIMC + 256 + 4 * lane);
  }

  __shared__ float s_logit[PARTC][CHUNK];
  __shared__ float s_w[PARTC][CHUNK];
  __shared__ float s_red[4][2 * PARTC];

  float m_run[PARTC], l_run[PARTC], ux[PARTC], uy[PARTC];
#pragma unroll
  for (int p = 0; p < PARTC; ++p) {
    m_run[p] = -1e30f; l_run[p] = 0.f; ux[p] = 0.f; uy[p] = 0.f;
  }

  for (int c0 = 0; c0 < NTOK; c0 += CHUNK) {
    const int cn = min(CHUNK, NTOK - c0);

    // Phase A: logits for this chunk (wave-per-token, lane-parallel over d)
    for (int nl = w; nl < cn; nl += 4) {
      const float* xr = xb + (size_t)(c0 + nl) * DIMC;
      float4 xa = *(const float4*)(xr + 4 * lane);
      float4 xc = *(const float4*)(xr + 256 + 4 * lane);
      float acc[PARTC];
#pragma unroll
      for (int p = 0; p < PARTC; ++p) {
        acc[p] = xa.x * pA[p].x + xa.y * pA[p].y + xa.z * pA[p].z + xa.w * pA[p].w
               + xc.x * pB[p].x + xc.y * pB[p].y + xc.z * pB[p].z + xc.w * pB[p].w;
      }
#pragma unroll
      for (int off = 32; off > 0; off >>= 1) {
#pragma unroll
        for (int p = 0; p < PARTC; ++p) acc[p] += __shfl_xor(acc[p], off);
      }
      if (lane == 0) {
#pragma unroll
        for (int p = 0; p < PARTC; ++p) s_logit[p][nl] = acc[p];
      }
    }
    __syncthreads();

    // Phase B1: chunk max + rescale factors (all threads, redundant+deterministic)
    float mnew[PARTC], f[PARTC];
#pragma unroll
    for (int p = 0; p < PARTC; ++p) {
      float cm = -1e30f;
      for (int i = 0; i < cn; ++i) cm = fmaxf(cm, s_logit[p][i]);
      mnew[p] = fmaxf(m_run[p], cm);
      f[p] = __expf(m_run[p] - mnew[p]);
    }
    // Phase B2: softmax weights for chunk
    if (tid < PARTC * CHUNK) {
      int p = tid >> 4, i = tid & 15;
      if (i < cn) s_w[p][i] = __expf(s_logit[p][i] - mnew[p]);
    }
    __syncthreads();

    // Phase B3: denominators + rescale + weighted accumulate (x re-read = L1/L2 hot)
#pragma unroll
    for (int p = 0; p < PARTC; ++p) {
      float ls = 0.f;
      for (int i = 0; i < cn; ++i) ls += s_w[p][i];
      l_run[p] = l_run[p] * f[p] + ls;
      ux[p] *= f[p]; uy[p] *= f[p];
      m_run[p] = mnew[p];
    }
    for (int i = 0; i < cn; ++i) {
      const float* xr = xb + (size_t)(c0 + i) * DIMC;
      float xa = xr[tid];
      float xc = xr[tid + 256];
#pragma unroll
      for (int p = 0; p < PARTC; ++p) {
        float ww = s_w[p][i];
        ux[p] += ww * xa;
        uy[p] += ww * xc;
      }
    }
  }

  // y = u / l / sqrt(512); then LayerNorm over d
  float ya[PARTC], yc[PARTC], s1[PARTC], s2[PARTC];
#pragma unroll
  for (int p = 0; p < PARTC; ++p) {
    float inv = 1.f / (l_run[p] * SCALING);
    ya[p] = ux[p] * inv;
    yc[p] = uy[p] * inv;
    s1[p] = ya[p] + yc[p];
    s2[p] = ya[p] * ya[p] + yc[p] * yc[p];
  }
#pragma unroll
  for (int off = 32; off > 0; off >>= 1) {
#pragma unroll
    for (int p = 0; p < PARTC; ++p) {
      s1[p] += __shfl_xor(s1[p], off);
      s2[p] += __shfl_xor(s2[p], off);
    }
  }
  if (lane == 0) {
#pragma unroll
    for (int p = 0; p < PARTC; ++p) {
      s_red[w][p] = s1[p];
      s_red[w][PARTC + p] = s2[p];
    }
  }
  __syncthreads();

  const float ga = g[tid], gc = g[tid + 256];
  const float ba = bta[tid], bc = bta[tid + 256];
  __hip_bfloat16* orow = outp + (size_t)b * PARTC * DIMC;
#pragma unroll
  for (int p = 0; p < PARTC; ++p) {
    float S = s_red[0][p] + s_red[1][p] + s_red[2][p] + s_red[3][p];
    float Q = s_red[0][PARTC + p] + s_red[1][PARTC + p] + s_red[2][PARTC + p] + s_red[3][PARTC + p];
    float mu = S * (1.f / 512.f);
    float var = Q * (1.f / 512.f) - mu * mu;
    float r = rsqrtf(var + LNEPS);
    orow[p * DIMC + tid]       = __float2bfloat16((ya[p] - mu) * r * ga + ba);
    orow[p * DIMC + tid + 256] = __float2bfloat16((yc[p] - mu) * r * gc + bc);
  }
}

// ---------------------------------------------------------------------------
// MFMA GEMM: C[M][N] = act(A[M][K] @ Bt[N][K]^T + bias)
// 256 threads = 4 waves in 2x2; wave tile (BM/2)x(BN/2); 16x16x32 bf16 MFMA.
// Reg-staged LDS with +16-elem pad (160B row stride: keeps b128 alignment,
// spreads the 16-lane row walk across banks).
// ---------------------------------------------------------------------------
template <int BM, int BN, bool GELU>
__global__ __launch_bounds__(256) void gemm_bt(
    const __hip_bfloat16* __restrict__ A,
    const __hip_bfloat16* __restrict__ Bt,
    const float* __restrict__ bias,
    void* __restrict__ Cv,
    int M, int N, int K)
{
  constexpr int BK = 64;
  constexpr int LDT = BK + 16; // 80 bf16 = 160B row stride
  __shared__ __align__(16) unsigned short Al[BM][LDT];
  __shared__ __align__(16) unsigned short Bl[BN][LDT];

  const int tid = threadIdx.x;
  const int w = tid >> 6, lane = tid & 63;
  const int wr = w >> 1, wc = w & 1;
  const int tm = blockIdx.y * BM, tn = blockIdx.x * BN;
  constexpr int FM = BM / 32, FN = BN / 32;

  f32x4 acc[FM][FN];
#pragma unroll
  for (int m = 0; m < FM; ++m)
#pragma unroll
    for (int n = 0; n < FN; ++n) acc[m][n] = (f32x4){0.f, 0.f, 0.f, 0.f};

  const int srow = tid >> 3;        // 0..31
  const int scol = (tid & 7) * 8;   // element offset in K

  for (int k0 = 0; k0 < K; k0 += BK) {
    __syncthreads();
#pragma unroll
    for (int r = 0; r < BM / 32; ++r) {
      int row = r * 32 + srow;
      *(int4*)(&Al[row][scol]) =
          *(const int4*)(A + (size_t)(tm + row) * K + k0 + scol);
    }
#pragma unroll
    for (int r = 0; r < BN / 32; ++r) {
      int row = r * 32 + srow;
      *(int4*)(&Bl[row][scol]) =
          *(const int4*)(Bt + (size_t)(tn + row) * K + k0 + scol);
    }
    __syncthreads();

#pragma unroll
    for (int kk = 0; kk < 2; ++kk) {
      const int ko = kk * 32 + (lane >> 4) * 8;
      bf16x8 af[FM], bfr[FN];
#pragma unroll
      for (int m = 0; m < FM; ++m)
        af[m] = *(const bf16x8*)(&Al[wr * (BM / 2) + m * 16 + (lane & 15)][ko]);
#pragma unroll
      for (int n = 0; n < FN; ++n)
        bfr[n] = *(const bf16x8*)(&Bl[wc * (BN / 2) + n * 16 + (lane & 15)][ko]);
#pragma unroll
      for (int m = 0; m < FM; ++m)
#pragma unroll
        for (int n = 0; n < FN; ++n)
          acc[m][n] = __builtin_amdgcn_mfma_f32_16x16x32_bf16(
              af[m], bfr[n], acc[m][n], 0, 0, 0);
    }
  }

  // Epilogue: C/D layout col = lane&15, row = (lane>>4)*4 + r  [m89-verified]
  const int cl = lane & 15, rg = (lane >> 4) * 4;
#pragma unroll
  for (int m = 0; m < FM; ++m) {
#pragma unroll
    for (int n = 0; n < FN; ++n) {
      int col = tn + wc * (BN / 2) + n * 16 + cl;
      float bv = bias[col];
#pragma unroll
      for (int r = 0; r < 4; ++r) {
        int row = tm + wr * (BM / 2) + m * 16 + rg + r;
        float v = acc[m][n][r] + bv;
        if (GELU) {
          v = 0.5f * v * (1.f + erff(v * 0.7071067811865476f));
          ((__hip_bfloat16*)Cv)[(size_t)row * N + col] = __float2bfloat16(v);
        } else {
          ((float*)Cv)[(size_t)row * N + col] = v;
        }
      }
    }
  }
}

// ---------------------------------------------------------------------------
extern "C" void kernel_launch(void* const* d_in, const int* in_sizes, int n_in,
                              void* d_out, int out_size, void* d_ws, size_t ws_size,
                              hipStream_t stream)
{
  const float* x   = (const float*)d_in[0];
  const float* pt  = (const float*)d_in[1];
  const float* g   = (const float*)d_in[2];
  const float* bta = (const float*)d_in[3];
  const float* W1  = (const float*)d_in[4];
  const float* b1  = (const float*)d_in[5];
  const float* W2  = (const float*)d_in[6];
  const float* b2  = (const float*)d_in[7];
  float* outp = (float*)d_out;

  char* ws = (char*)d_ws;
  __hip_bfloat16* W1T = (__hip_bfloat16*)(ws);                         // 2048x512  bf16 (2 MB)
  __hip_bfloat16* W2T = (__hip_bfloat16*)(ws + 2097152);               // 512x2048  bf16 (2 MB)
  __hip_bfloat16* LNO = (__hip_bfloat16*)(ws + 4194304);               // 6144x512  bf16 (6 MB)
  __hip_bfloat16* H   = (__hip_bfloat16*)(ws + 4194304 + 6291456);     // 6144x2048 bf16 (24 MB)

  // K0: W1 (512x2048) -> W1T (2048x512); W2 (2048x512) -> W2T (512x2048)
  transpose_f32_bf16<<<dim3(2048 / 32, 512 / 32), dim3(32, 8), 0, stream>>>(W1, W1T, 512, 2048);
  transpose_f32_bf16<<<dim3(512 / 32, 2048 / 32), dim3(32, 8), 0, stream>>>(W2, W2T, 2048, 512);

  // K1: fused attention + LN -> LNO
  attn_ln_k<<<1024, 256, 0, stream>>>(x, pt, g, bta, LNO);

  // K2: h = gelu(LNO @ W1 + b1) -> H (bf16)
  gemm_bt<128, 128, true><<<dim3(2048 / 128, 6144 / 128), 256, 0, stream>>>(
      LNO, W1T, b1, (void*)H, 6144, 2048, 512);

  // K3: out = H @ W2 + b2 -> d_out (f32)
  gemm_bt<64, 64, false><<<dim3(512 / 64, 6144 / 64), 256, 0, stream>>>(
      H, W2T, b2, (void*)outp, 6144, 512, 2048);
}

// Round 4
// 262.965 us; speedup vs baseline: 1.4396x; 1.4396x over previous
//
#include <hip/hip_runtime.h>
#include <hip/hip_bf16.h>

// Problem constants
constexpr int   DIMC  = 512;
constexpr int   PARTC = 6;
constexpr int   NTOK  = 162;
constexpr float SCALING = 22.62741699796952f; // sqrt(512)
constexpr float LNEPS   = 1e-5f;
constexpr int   CHUNK  = 16;                  // tokens per chunk (32KB LDS)
constexpr int   NCH    = (NTOK + CHUNK - 1) / CHUNK;  // 11 (last cn=2)

typedef __attribute__((ext_vector_type(8))) short bf16x8;
typedef __attribute__((ext_vector_type(4))) float f32x4;

// raw barrier + counted waits (m201 template discipline)
#define BAR_LGKM() do { asm volatile("s_waitcnt lgkmcnt(0)" ::: "memory"); \
                        __builtin_amdgcn_sched_barrier(0);                 \
                        __builtin_amdgcn_s_barrier(); } while (0)
#define BAR_ALL()  do { asm volatile("s_waitcnt vmcnt(0) lgkmcnt(0)" ::: "memory"); \
                        __builtin_amdgcn_sched_barrier(0);                 \
                        __builtin_amdgcn_s_barrier(); } while (0)

__device__ __forceinline__ void gload16(const float* g, float* l) {
  __builtin_amdgcn_global_load_lds(
      (const __attribute__((address_space(1))) void*)g,
      (__attribute__((address_space(3))) void*)l, 16, 0, 0);
}

// ---------------------------------------------------------------------------
// K0: transpose f32 [R][C] -> bf16 [C][R]
// ---------------------------------------------------------------------------
__global__ __launch_bounds__(256) void transpose_f32_bf16(
    const float* __restrict__ in, __hip_bfloat16* __restrict__ outp, int R, int C)
{
  __shared__ float tile[32][33];
  const int tx = threadIdx.x, ty = threadIdx.y;
  const int bx = blockIdx.x, by = blockIdx.y;
  const int c = bx * 32 + tx;
#pragma unroll
  for (int i = 0; i < 32; i += 8) {
    int r = by * 32 + ty + i;
    tile[ty + i][tx] = in[(size_t)r * C + c];
  }
  __syncthreads();
#pragma unroll
  for (int i = 0; i < 32; i += 8) {
    outp[(size_t)(bx * 32 + ty + i) * R + by * 32 + tx] =
        __float2bfloat16(tile[tx][ty + i]);
  }
}

// ---------------------------------------------------------------------------
// K1 v2: fused attention (online softmax) + /sqrt(512) + LayerNorm
// One block per b, 256 threads (4 waves). Per 16-token chunk:
//   stage:  global_load_lds width-16, double-buffered (x read ONCE from HBM)
//   A: logits from LDS (wave-per-token, lane-parallel dot, shfl reduce)
//   B: 6 owner threads do softmax bookkeeping (max/exp/rescale), publish w,f
//   C: all threads rescale + weighted-accumulate from LDS (thread t owns
//      dims t and t+256 of all 6 part rows)
// ---------------------------------------------------------------------------
__global__ __launch_bounds__(256) void attn_ln_k(
    const float* __restrict__ x,     // [1024][162][512]
    const float* __restrict__ pt,    // [6][512]
    const float* __restrict__ g,     // [512]
    const float* __restrict__ bta,   // [512]
    __hip_bfloat16* __restrict__ outp)
{
  const int b = blockIdx.x;
  const int tid = threadIdx.x;
  const int w = tid >> 6;
  const int lane = tid & 63;
  const float* __restrict__ xb = x + (size_t)b * (NTOK * DIMC);

  __shared__ __align__(16) float xs[2][CHUNK][DIMC];   // 2 x 32 KB
  __shared__ float s_logit[PARTC][CHUNK];
  __shared__ __align__(16) float s_w[PARTC][CHUNK];
  __shared__ float s_f[PARTC];
  __shared__ float s_l[PARTC];
  __shared__ float s_red[4][2 * PARTC];

  // pt fragments: lane covers cols [4l,4l+4) and [256+4l, 256+4l+4)
  float4 pA[PARTC], pB[PARTC];
#pragma unroll
  for (int p = 0; p < PARTC; ++p) {
    pA[p] = *(const float4*)(pt + p * DIMC + 4 * lane);
    pB[p] = *(const float4*)(pt + p * DIMC + 256 + 4 * lane);
  }

  // softmax owner state (live only in threads 0..5)
  float m_run = -1e30f, l_run = 0.f;
  // PV accumulators: thread owns dims tid and tid+256
  float ux[PARTC], uy[PARTC];
#pragma unroll
  for (int p = 0; p < PARTC; ++p) { ux[p] = 0.f; uy[p] = 0.f; }

  // stage chunk c into xs[nb]: wave w stages rows [4w,4w+4) = 8 KB = 8 issues
  auto stage = [&](int c, int nb) {
    const int maxoff = NTOK * DIMC - 4;
    const int base = (c * CHUNK + w * 4) * DIMC + lane * 4;
    float* dst = &xs[nb][0][0] + w * (4 * DIMC);
#pragma unroll
    for (int r = 0; r < 8; ++r) {
      int off = base + r * 256;
      off = min(off, maxoff);               // clamp tail chunk in-bounds
      gload16(xb + off, dst + r * 256);
    }
  };

  stage(0, 0);
  int buf = 0;

  for (int c = 0; c < NCH; ++c) {
    const int cn = min(CHUNK, NTOK - c * CHUNK);
    BAR_ALL();   // chunk c staged; prior Phase-C LDS reads drained

    if (c + 1 < NCH) stage(c + 1, buf ^ 1);   // in flight across A/B/C

    // ---- Phase A: logits (wave-per-token) ----
    const float* bufp = &xs[buf][0][0];
    for (int nl = w; nl < cn; nl += 4) {
      const float* xr = bufp + nl * DIMC;
      float4 xa = *(const float4*)(xr + 4 * lane);
      float4 xc = *(const float4*)(xr + 256 + 4 * lane);
      float acc[PARTC];
#pragma unroll
      for (int p = 0; p < PARTC; ++p) {
        acc[p] = xa.x * pA[p].x + xa.y * pA[p].y + xa.z * pA[p].z + xa.w * pA[p].w
               + xc.x * pB[p].x + xc.y * pB[p].y + xc.z * pB[p].z + xc.w * pB[p].w;
      }
#pragma unroll
      for (int off = 32; off > 0; off >>= 1) {
#pragma unroll
        for (int p = 0; p < PARTC; ++p) acc[p] += __shfl_xor(acc[p], off);
      }
      if (lane == 0) {
#pragma unroll
        for (int p = 0; p < PARTC; ++p) s_logit[p][nl] = acc[p];
      }
    }
    BAR_LGKM();

    // ---- Phase B: softmax bookkeeping (6 owner threads) ----
    if (tid < PARTC) {
      const int p = tid;
      float cm = -1e30f;
      for (int i = 0; i < cn; ++i) cm = fmaxf(cm, s_logit[p][i]);
      float mnew = fmaxf(m_run, cm);
      float f = __expf(m_run - mnew);
      m_run = mnew;
      float ls = 0.f;
#pragma unroll
      for (int i = 0; i < CHUNK; ++i) {
        float wv = (i < cn) ? __expf(s_logit[p][i] - mnew) : 0.f;
        s_w[p][i] = wv;
        ls += wv;
      }
      l_run = l_run * f + ls;
      s_f[p] = f;
    }
    BAR_LGKM();

    // ---- Phase C: rescale + weighted accumulate (all threads) ----
    {
      float fl[PARTC];
#pragma unroll
      for (int p = 0; p < PARTC; ++p) fl[p] = s_f[p];
#pragma unroll
      for (int p = 0; p < PARTC; ++p) { ux[p] *= fl[p]; uy[p] *= fl[p]; }
#pragma unroll
      for (int i0 = 0; i0 < CHUNK; i0 += 4) {
        float4 wv[PARTC];
#pragma unroll
        for (int p = 0; p < PARTC; ++p) wv[p] = *(const float4*)&s_w[p][i0];
#pragma unroll
        for (int j = 0; j < 4; ++j) {
          const float* xr = bufp + (i0 + j) * DIMC;
          float xa = xr[tid];
          float xc = xr[tid + 256];
#pragma unroll
          for (int p = 0; p < PARTC; ++p) {
            ux[p] += wv[p][j] * xa;
            uy[p] += wv[p][j] * xc;
          }
        }
      }
    }
    buf ^= 1;
  }

  // publish denominators
  if (tid < PARTC) s_l[tid] = l_run;
  __syncthreads();

  // y = u / l / sqrt(512); then LayerNorm over d
  float ya[PARTC], yc[PARTC], s1[PARTC], s2[PARTC];
#pragma unroll
  for (int p = 0; p < PARTC; ++p) {
    float inv = 1.f / (s_l[p] * SCALING);
    ya[p] = ux[p] * inv;
    yc[p] = uy[p] * inv;
    s1[p] = ya[p] + yc[p];
    s2[p] = ya[p] * ya[p] + yc[p] * yc[p];
  }
#pragma unroll
  for (int off = 32; off > 0; off >>= 1) {
#pragma unroll
    for (int p = 0; p < PARTC; ++p) {
      s1[p] += __shfl_xor(s1[p], off);
      s2[p] += __shfl_xor(s2[p], off);
    }
  }
  if (lane == 0) {
#pragma unroll
    for (int p = 0; p < PARTC; ++p) {
      s_red[w][p] = s1[p];
      s_red[w][PARTC + p] = s2[p];
    }
  }
  __syncthreads();

  const float ga = g[tid], gc = g[tid + 256];
  const float ba = bta[tid], bc = bta[tid + 256];
  __hip_bfloat16* orow = outp + (size_t)b * PARTC * DIMC;
#pragma unroll
  for (int p = 0; p < PARTC; ++p) {
    float S = s_red[0][p] + s_red[1][p] + s_red[2][p] + s_red[3][p];
    float Q = s_red[0][PARTC + p] + s_red[1][PARTC + p] + s_red[2][PARTC + p] + s_red[3][PARTC + p];
    float mu = S * (1.f / 512.f);
    float var = Q * (1.f / 512.f) - mu * mu;
    float r = rsqrtf(var + LNEPS);
    orow[p * DIMC + tid]       = __float2bfloat16((ya[p] - mu) * r * ga + ba);
    orow[p * DIMC + tid + 256] = __float2bfloat16((yc[p] - mu) * r * gc + bc);
  }
}

// ---------------------------------------------------------------------------
// MFMA GEMM: C[M][N] = act(A[M][K] @ Bt[N][K]^T + bias)   (unchanged)
// ---------------------------------------------------------------------------
template <int BM, int BN, bool GELU>
__global__ __launch_bounds__(256) void gemm_bt(
    const __hip_bfloat16* __restrict__ A,
    const __hip_bfloat16* __restrict__ Bt,
    const float* __restrict__ bias,
    void* __restrict__ Cv,
    int M, int N, int K)
{
  constexpr int BK = 64;
  constexpr int LDT = BK + 16; // 80 bf16 = 160B row stride
  __shared__ __align__(16) unsigned short Al[BM][LDT];
  __shared__ __align__(16) unsigned short Bl[BN][LDT];

  const int tid = threadIdx.x;
  const int w = tid >> 6, lane = tid & 63;
  const int wr = w >> 1, wc = w & 1;
  const int tm = blockIdx.y * BM, tn = blockIdx.x * BN;
  constexpr int FM = BM / 32, FN = BN / 32;

  f32x4 acc[FM][FN];
#pragma unroll
  for (int m = 0; m < FM; ++m)
#pragma unroll
    for (int n = 0; n < FN; ++n) acc[m][n] = (f32x4){0.f, 0.f, 0.f, 0.f};

  const int srow = tid >> 3;        // 0..31
  const int scol = (tid & 7) * 8;   // element offset in K

  for (int k0 = 0; k0 < K; k0 += BK) {
    __syncthreads();
#pragma unroll
    for (int r = 0; r < BM / 32; ++r) {
      int row = r * 32 + srow;
      *(int4*)(&Al[row][scol]) =
          *(const int4*)(A + (size_t)(tm + row) * K + k0 + scol);
    }
#pragma unroll
    for (int r = 0; r < BN / 32; ++r) {
      int row = r * 32 + srow;
      *(int4*)(&Bl[row][scol]) =
          *(const int4*)(Bt + (size_t)(tn + row) * K + k0 + scol);
    }
    __syncthreads();

#pragma unroll
    for (int kk = 0; kk < 2; ++kk) {
      const int ko = kk * 32 + (lane >> 4) * 8;
      bf16x8 af[FM], bfr[FN];
#pragma unroll
      for (int m = 0; m < FM; ++m)
        af[m] = *(const bf16x8*)(&Al[wr * (BM / 2) + m * 16 + (lane & 15)][ko]);
#pragma unroll
      for (int n = 0; n < FN; ++n)
        bfr[n] = *(const bf16x8*)(&Bl[wc * (BN / 2) + n * 16 + (lane & 15)][ko]);
#pragma unroll
      for (int m = 0; m < FM; ++m)
#pragma unroll
        for (int n = 0; n < FN; ++n)
          acc[m][n] = __builtin_amdgcn_mfma_f32_16x16x32_bf16(
              af[m], bfr[n], acc[m][n], 0, 0, 0);
    }
  }

  // Epilogue: C/D layout col = lane&15, row = (lane>>4)*4 + r  [m89-verified]
  const int cl = lane & 15, rg = (lane >> 4) * 4;
#pragma unroll
  for (int m = 0; m < FM; ++m) {
#pragma unroll
    for (int n = 0; n < FN; ++n) {
      int col = tn + wc * (BN / 2) + n * 16 + cl;
      float bv = bias[col];
#pragma unroll
      for (int r = 0; r < 4; ++r) {
        int row = tm + wr * (BM / 2) + m * 16 + rg + r;
        float v = acc[m][n][r] + bv;
        if (GELU) {
          v = 0.5f * v * (1.f + erff(v * 0.7071067811865476f));
          ((__hip_bfloat16*)Cv)[(size_t)row * N + col] = __float2bfloat16(v);
        } else {
          ((float*)Cv)[(size_t)row * N + col] = v;
        }
      }
    }
  }
}

// ---------------------------------------------------------------------------
extern "C" void kernel_launch(void* const* d_in, const int* in_sizes, int n_in,
                              void* d_out, int out_size, void* d_ws, size_t ws_size,
                              hipStream_t stream)
{
  const float* x   = (const float*)d_in[0];
  const float* pt  = (const float*)d_in[1];
  const float* g   = (const float*)d_in[2];
  const float* bta = (const float*)d_in[3];
  const float* W1  = (const float*)d_in[4];
  const float* b1  = (const float*)d_in[5];
  const float* W2  = (const float*)d_in[6];
  const float* b2  = (const float*)d_in[7];
  float* outp = (float*)d_out;

  char* ws = (char*)d_ws;
  __hip_bfloat16* W1T = (__hip_bfloat16*)(ws);                         // 2048x512  bf16 (2 MB)
  __hip_bfloat16* W2T = (__hip_bfloat16*)(ws + 2097152);               // 512x2048  bf16 (2 MB)
  __hip_bfloat16* LNO = (__hip_bfloat16*)(ws + 4194304);               // 6144x512  bf16 (6 MB)
  __hip_bfloat16* H   = (__hip_bfloat16*)(ws + 4194304 + 6291456);     // 6144x2048 bf16 (24 MB)

  // K0: W1 (512x2048) -> W1T (2048x512); W2 (2048x512) -> W2T (512x2048)
  transpose_f32_bf16<<<dim3(2048 / 32, 512 / 32), dim3(32, 8), 0, stream>>>(W1, W1T, 512, 2048);
  transpose_f32_bf16<<<dim3(512 / 32, 2048 / 32), dim3(32, 8), 0, stream>>>(W2, W2T, 2048, 512);

  // K1: fused attention + LN -> LNO
  attn_ln_k<<<1024, 256, 0, stream>>>(x, pt, g, bta, LNO);

  // K2: h = gelu(LNO @ W1 + b1) -> H (bf16)
  gemm_bt<128, 128, true><<<dim3(2048 / 128, 6144 / 128), 256, 0, stream>>>(
      LNO, W1T, b1, (void*)H, 6144, 2048, 512);

  // K3: out = H @ W2 + b2 -> d_out (f32)
  gemm_bt<64, 64, false><<<dim3(512 / 64, 6144 / 64), 256, 0, stream>>>(
      H, W2T, b2, (void*)outp, 6144, 512, 2048);
}

// Round 5
// 245.276 us; speedup vs baseline: 1.5434x; 1.0721x over previous
//
#include <hip/hip_runtime.h>
#include <hip/hip_bf16.h>

// Problem constants
constexpr int   DIMC  = 512;
constexpr int   PARTC = 6;
constexpr int   NTOK  = 162;
constexpr float SCALING = 22.62741699796952f; // sqrt(512)
constexpr float LNEPS   = 1e-5f;

typedef __attribute__((ext_vector_type(8))) short bf16x8;
typedef __attribute__((ext_vector_type(4))) float f32x4;

// ---------------------------------------------------------------------------
// K0: transpose f32 [R][C] -> bf16 [C][R]
// ---------------------------------------------------------------------------
__global__ __launch_bounds__(256) void transpose_f32_bf16(
    const float* __restrict__ in, __hip_bfloat16* __restrict__ outp, int R, int C)
{
  __shared__ float tile[32][33];
  const int tx = threadIdx.x, ty = threadIdx.y;
  const int bx = blockIdx.x, by = blockIdx.y;
  const int c = bx * 32 + tx;
#pragma unroll
  for (int i = 0; i < 32; i += 8) {
    int r = by * 32 + ty + i;
    tile[ty + i][tx] = in[(size_t)r * C + c];
  }
  __syncthreads();
#pragma unroll
  for (int i = 0; i < 32; i += 8) {
    outp[(size_t)(bx * 32 + ty + i) * R + by * 32 + tx] =
        __float2bfloat16(tile[tx][ty + i]);
  }
}

// ---------------------------------------------------------------------------
// K1 v3: fused attention + /sqrt(512) + LayerNorm.  Block = one b, 256 thr.
// NO x staging (per-b x = 332KB; 2nd pass hits L2/L3).  Two block-local
// passes + parallel softmax; 4 barriers total; ~9KB LDS -> 4 blocks/CU.
//   P1: wave-per-token logits (float4 global loads, shfl reduce) -> LDS
//   SM: 6 groups x 32 threads: max / exp / sum (weights unnormalized)
//   P2: thread owns dims (2t,2t+1); streams 162 rows as float2; 24 FMA/row
//   LN: normalize by l*sqrt(512), mean/var reduce, gamma/beta, bf16 out
// ---------------------------------------------------------------------------
__global__ __launch_bounds__(256, 4) void attn_ln_k(
    const float* __restrict__ x,     // [1024][162][512]
    const float* __restrict__ pt,    // [6][512]
    const float* __restrict__ g,     // [512]
    const float* __restrict__ bta,   // [512]
    __hip_bfloat16* __restrict__ outp)
{
  const int b = blockIdx.x;
  const int tid = threadIdx.x;
  const int w = tid >> 6;
  const int lane = tid & 63;
  const float* __restrict__ xb = x + (size_t)b * (NTOK * DIMC);

  __shared__ float s_logit[PARTC][168];
  __shared__ __align__(16) float s_w[PARTC][164];
  __shared__ float s_l[PARTC];
  __shared__ float s_red[4][2 * PARTC];

  // ---- P1: logits.  Lane covers dims [8l, 8l+8). ----
  float4 pA[PARTC], pB[PARTC];
#pragma unroll
  for (int p = 0; p < PARTC; ++p) {
    pA[p] = *(const float4*)(pt + p * DIMC + 8 * lane);
    pB[p] = *(const float4*)(pt + p * DIMC + 8 * lane + 4);
  }

  for (int n = w; n < NTOK; n += 4) {
    const float* xr = xb + n * DIMC;
    float4 xa = *(const float4*)(xr + 8 * lane);
    float4 xc = *(const float4*)(xr + 8 * lane + 4);
    float acc[PARTC];
#pragma unroll
    for (int p = 0; p < PARTC; ++p) {
      acc[p] = xa.x * pA[p].x + xa.y * pA[p].y + xa.z * pA[p].z + xa.w * pA[p].w
             + xc.x * pB[p].x + xc.y * pB[p].y + xc.z * pB[p].z + xc.w * pB[p].w;
    }
#pragma unroll
    for (int off = 32; off > 0; off >>= 1) {
#pragma unroll
      for (int p = 0; p < PARTC; ++p) acc[p] += __shfl_xor(acc[p], off);
    }
    if (lane == 0) {
#pragma unroll
      for (int p = 0; p < PARTC; ++p) s_logit[p][n] = acc[p];
    }
  }
  __syncthreads();

  // ---- Softmax: group (32 threads) per part. shfl masks <=16 stay in-group.
  if (tid < PARTC * 32) {
    const int grp = tid >> 5, gl = tid & 31;
    float m = -1e30f;
    for (int i = gl; i < NTOK; i += 32) m = fmaxf(m, s_logit[grp][i]);
#pragma unroll
    for (int off = 16; off > 0; off >>= 1) m = fmaxf(m, __shfl_xor(m, off));
    float s = 0.f;
    for (int i = gl; i < NTOK; i += 32) {
      float wv = __expf(s_logit[grp][i] - m);
      s_w[grp][i] = wv;
      s += wv;
    }
#pragma unroll
    for (int off = 16; off > 0; off >>= 1) s += __shfl_xor(s, off);
    if (gl == 0) s_l[grp] = s;
  }
  __syncthreads();

  // ---- P2: weighted accumulate.  Thread owns dims (2t, 2t+1). ----
  float2 u[PARTC];
#pragma unroll
  for (int p = 0; p < PARTC; ++p) { u[p].x = 0.f; u[p].y = 0.f; }

  const float* xcol = xb + 2 * tid;
  for (int n0 = 0; n0 < 160; n0 += 4) {
    f32x4 wv[PARTC];
#pragma unroll
    for (int p = 0; p < PARTC; ++p) wv[p] = *(const f32x4*)&s_w[p][n0];
#pragma unroll
    for (int j = 0; j < 4; ++j) {
      float2 xv = *(const float2*)(xcol + (n0 + j) * DIMC);
#pragma unroll
      for (int p = 0; p < PARTC; ++p) {
        u[p].x += wv[p][j] * xv.x;
        u[p].y += wv[p][j] * xv.y;
      }
    }
  }
#pragma unroll
  for (int n = 160; n < NTOK; ++n) {
    float2 xv = *(const float2*)(xcol + n * DIMC);
#pragma unroll
    for (int p = 0; p < PARTC; ++p) {
      float wv = s_w[p][n];
      u[p].x += wv * xv.x;
      u[p].y += wv * xv.y;
    }
  }

  // ---- LN: y = u/(l*sqrt(512)); normalize over d. ----
  float y0[PARTC], y1[PARTC], s1[PARTC], s2[PARTC];
#pragma unroll
  for (int p = 0; p < PARTC; ++p) {
    float inv = 1.f / (s_l[p] * SCALING);
    y0[p] = u[p].x * inv;
    y1[p] = u[p].y * inv;
    s1[p] = y0[p] + y1[p];
    s2[p] = y0[p] * y0[p] + y1[p] * y1[p];
  }
#pragma unroll
  for (int off = 32; off > 0; off >>= 1) {
#pragma unroll
    for (int p = 0; p < PARTC; ++p) {
      s1[p] += __shfl_xor(s1[p], off);
      s2[p] += __shfl_xor(s2[p], off);
    }
  }
  if (lane == 0) {
#pragma unroll
    for (int p = 0; p < PARTC; ++p) {
      s_red[w][p] = s1[p];
      s_red[w][PARTC + p] = s2[p];
    }
  }
  __syncthreads();

  const float ga0 = g[2 * tid], ga1 = g[2 * tid + 1];
  const float bb0 = bta[2 * tid], bb1 = bta[2 * tid + 1];
  __hip_bfloat16* orow = outp + (size_t)b * PARTC * DIMC;
#pragma unroll
  for (int p = 0; p < PARTC; ++p) {
    float S = s_red[0][p] + s_red[1][p] + s_red[2][p] + s_red[3][p];
    float Q = s_red[0][PARTC + p] + s_red[1][PARTC + p] + s_red[2][PARTC + p] + s_red[3][PARTC + p];
    float mu = S * (1.f / 512.f);
    float var = Q * (1.f / 512.f) - mu * mu;
    float r = rsqrtf(var + LNEPS);
    __hip_bfloat162 hv;
    hv.x = __float2bfloat16((y0[p] - mu) * r * ga0 + bb0);
    hv.y = __float2bfloat16((y1[p] - mu) * r * ga1 + bb1);
    *(__hip_bfloat162*)(orow + p * DIMC + 2 * tid) = hv;
  }
}

// ---------------------------------------------------------------------------
// MFMA GEMM: C[M][N] = act(A[M][K] @ Bt[N][K]^T + bias)   (unchanged)
// ---------------------------------------------------------------------------
template <int BM, int BN, bool GELU>
__global__ __launch_bounds__(256) void gemm_bt(
    const __hip_bfloat16* __restrict__ A,
    const __hip_bfloat16* __restrict__ Bt,
    const float* __restrict__ bias,
    void* __restrict__ Cv,
    int M, int N, int K)
{
  constexpr int BK = 64;
  constexpr int LDT = BK + 16; // 80 bf16 = 160B row stride
  __shared__ __align__(16) unsigned short Al[BM][LDT];
  __shared__ __align__(16) unsigned short Bl[BN][LDT];

  const int tid = threadIdx.x;
  const int w = tid >> 6, lane = tid & 63;
  const int wr = w >> 1, wc = w & 1;
  const int tm = blockIdx.y * BM, tn = blockIdx.x * BN;
  constexpr int FM = BM / 32, FN = BN / 32;

  f32x4 acc[FM][FN];
#pragma unroll
  for (int m = 0; m < FM; ++m)
#pragma unroll
    for (int n = 0; n < FN; ++n) acc[m][n] = (f32x4){0.f, 0.f, 0.f, 0.f};

  const int srow = tid >> 3;        // 0..31
  const int scol = (tid & 7) * 8;   // element offset in K

  for (int k0 = 0; k0 < K; k0 += BK) {
    __syncthreads();
#pragma unroll
    for (int r = 0; r < BM / 32; ++r) {
      int row = r * 32 + srow;
      *(int4*)(&Al[row][scol]) =
          *(const int4*)(A + (size_t)(tm + row) * K + k0 + scol);
    }
#pragma unroll
    for (int r = 0; r < BN / 32; ++r) {
      int row = r * 32 + srow;
      *(int4*)(&Bl[row][scol]) =
          *(const int4*)(Bt + (size_t)(tn + row) * K + k0 + scol);
    }
    __syncthreads();

#pragma unroll
    for (int kk = 0; kk < 2; ++kk) {
      const int ko = kk * 32 + (lane >> 4) * 8;
      bf16x8 af[FM], bfr[FN];
#pragma unroll
      for (int m = 0; m < FM; ++m)
        af[m] = *(const bf16x8*)(&Al[wr * (BM / 2) + m * 16 + (lane & 15)][ko]);
#pragma unroll
      for (int n = 0; n < FN; ++n)
        bfr[n] = *(const bf16x8*)(&Bl[wc * (BN / 2) + n * 16 + (lane & 15)][ko]);
#pragma unroll
      for (int m = 0; m < FM; ++m)
#pragma unroll
        for (int n = 0; n < FN; ++n)
          acc[m][n] = __builtin_amdgcn_mfma_f32_16x16x32_bf16(
              af[m], bfr[n], acc[m][n], 0, 0, 0);
    }
  }

  // Epilogue: C/D layout col = lane&15, row = (lane>>4)*4 + r  [m89-verified]
  const int cl = lane & 15, rg = (lane >> 4) * 4;
#pragma unroll
  for (int m = 0; m < FM; ++m) {
#pragma unroll
    for (int n = 0; n < FN; ++n) {
      int col = tn + wc * (BN / 2) + n * 16 + cl;
      float bv = bias[col];
#pragma unroll
      for (int r = 0; r < 4; ++r) {
        int row = tm + wr * (BM / 2) + m * 16 + rg + r;
        float v = acc[m][n][r] + bv;
        if (GELU) {
          v = 0.5f * v * (1.f + erff(v * 0.7071067811865476f));
          ((__hip_bfloat16*)Cv)[(size_t)row * N + col] = __float2bfloat16(v);
        } else {
          ((float*)Cv)[(size_t)row * N + col] = v;
        }
      }
    }
  }
}

// ---------------------------------------------------------------------------
extern "C" void kernel_launch(void* const* d_in, const int* in_sizes, int n_in,
                              void* d_out, int out_size, void* d_ws, size_t ws_size,
                              hipStream_t stream)
{
  const float* x   = (const float*)d_in[0];
  const float* pt  = (const float*)d_in[1];
  const float* g   = (const float*)d_in[2];
  const float* bta = (const float*)d_in[3];
  const float* W1  = (const float*)d_in[4];
  const float* b1  = (const float*)d_in[5];
  const float* W2  = (const float*)d_in[6];
  const float* b2  = (const float*)d_in[7];
  float* outp = (float*)d_out;

  char* ws = (char*)d_ws;
  __hip_bfloat16* W1T = (__hip_bfloat16*)(ws);                         // 2048x512  bf16 (2 MB)
  __hip_bfloat16* W2T = (__hip_bfloat16*)(ws + 2097152);               // 512x2048  bf16 (2 MB)
  __hip_bfloat16* LNO = (__hip_bfloat16*)(ws + 4194304);               // 6144x512  bf16 (6 MB)
  __hip_bfloat16* H   = (__hip_bfloat16*)(ws + 4194304 + 6291456);     // 6144x2048 bf16 (24 MB)

  // K0: W1 (512x2048) -> W1T (2048x512); W2 (2048x512) -> W2T (512x2048)
  transpose_f32_bf16<<<dim3(2048 / 32, 512 / 32), dim3(32, 8), 0, stream>>>(W1, W1T, 512, 2048);
  transpose_f32_bf16<<<dim3(512 / 32, 2048 / 32), dim3(32, 8), 0, stream>>>(W2, W2T, 2048, 512);

  // K1: fused attention + LN -> LNO
  attn_ln_k<<<1024, 256, 0, stream>>>(x, pt, g, bta, LNO);

  // K2: h = gelu(LNO @ W1 + b1) -> H (bf16)
  gemm_bt<128, 128, true><<<dim3(2048 / 128, 6144 / 128), 256, 0, stream>>>(
      LNO, W1T, b1, (void*)H, 6144, 2048, 512);

  // K3: out = H @ W2 + b2 -> d_out (f32)
  gemm_bt<64, 64, false><<<dim3(512 / 64, 6144 / 64), 256, 0, stream>>>(
      H, W2T, b2, (void*)outp, 6144, 512, 2048);
}